// Round 2
// baseline (1081.770 us; speedup 1.0000x reference)
//
#include <hip/hip_runtime.h>
#include <math.h>

#define DIM 128

__device__ __forceinline__ float gelu_exact(float v) {
    return 0.5f * v * (1.0f + erff(v * 0.70710678118654752f));
}

// ---------------- graph build ----------------

__global__ void deg_cnt_kernel(const int* __restrict__ dst,
                               const float* __restrict__ w,
                               float* __restrict__ degf, int* __restrict__ cnt, int E) {
    int e = blockIdx.x * blockDim.x + threadIdx.x;
    if (e >= E) return;
    int d = dst[e];
    atomicAdd(&degf[d], w[e]);
    atomicAdd(&cnt[d], 1);
}

__global__ void dinv_kernel(float* __restrict__ degf, int BN) {
    int n = blockIdx.x * blockDim.x + threadIdx.x;
    if (n >= BN) return;
    degf[n] = rsqrtf(degf[n] + 1.0f);
}

// single-workgroup exclusive scan of cnt -> ptr (and cursor copy), 8 elems/thread/chunk
__global__ void scan_kernel(const int* __restrict__ cnt, int* __restrict__ ptr,
                            int* __restrict__ cursor, int BN) {
    __shared__ int lds[256];
    __shared__ int carry_s;
    int tid = threadIdx.x;
    if (tid == 0) carry_s = 0;
    __syncthreads();
    for (int base = 0; base < BN; base += 2048) {
        int v[8];
        int idx0 = base + tid * 8;
        int tsum = 0;
#pragma unroll
        for (int j = 0; j < 8; j++) {
            int ii = idx0 + j;
            v[j] = (ii < BN) ? cnt[ii] : 0;
            tsum += v[j];
        }
        lds[tid] = tsum;
        __syncthreads();
#pragma unroll
        for (int off = 1; off < 256; off <<= 1) {
            int t = 0;
            if (tid >= off) t = lds[tid - off];
            __syncthreads();
            if (tid >= off) lds[tid] += t;
            __syncthreads();
        }
        int excl = lds[tid] - tsum + carry_s;
        int total = lds[255] + carry_s;
        __syncthreads();
#pragma unroll
        for (int j = 0; j < 8; j++) {
            int ii = idx0 + j;
            if (ii < BN) { ptr[ii] = excl; cursor[ii] = excl; }
            excl += v[j];
        }
        if (tid == 0) carry_s = total;
        __syncthreads();
    }
}

__global__ void fill_kernel(const int* __restrict__ ei, const float* __restrict__ w,
                            const float* __restrict__ dinv, int* __restrict__ cursor,
                            int* __restrict__ csr_src, float* __restrict__ csr_nrm, int E) {
    int e = blockIdx.x * blockDim.x + threadIdx.x;
    if (e >= E) return;
    int s = ei[e];
    int d = ei[(size_t)E + e];
    int pos = atomicAdd(&cursor[d], 1);
    csr_src[pos] = s;
    csr_nrm[pos] = dinv[s] * w[e] * dinv[d];
}

// ---------------- GEMM: [BN,128] @ [128,128], fp32 vector ALU ----------------
// MODE 0: out = X@W            MODE 1: out += 0.3f*(X@W + bias)

template <int MODE>
__global__ __launch_bounds__(256) void gemm128_kernel(const float* __restrict__ X,
                                                      const float* __restrict__ W,
                                                      const float* __restrict__ bias,
                                                      float* __restrict__ out, int BN) {
    __shared__ float Wl[64 * 132];  // K-chunk 64 x 128, row pad to 132 floats
    __shared__ float xs[32 * 66];   // 32 rows x 64-col chunk, pad 66

    int tid = threadIdx.x;
    int cg = tid & 15;   // column group: 8 consecutive cols
    int rg = tid >> 4;   // row group: 2 consecutive rows
    int row0 = blockIdx.x * 32;

    float acc[2][8];
#pragma unroll
    for (int i = 0; i < 2; i++)
#pragma unroll
        for (int j = 0; j < 8; j++) acc[i][j] = 0.0f;

    for (int kk = 0; kk < 128; kk += 64) {
        // stage W chunk: 64x128 floats = 2048 float4, 8 per thread
#pragma unroll
        for (int i = 0; i < 8; i++) {
            int f4 = tid + i * 256;
            int r = f4 >> 5;     // 32 float4 per row
            int c4 = f4 & 31;
            float4 val = ((const float4*)(W + (size_t)(kk + r) * 128))[c4];
            ((float4*)(Wl + r * 132))[c4] = val;
        }
        // stage x chunk: 32x64 floats = 1024 float2, 4 per thread
#pragma unroll
        for (int i = 0; i < 4; i++) {
            int f2 = tid + i * 256;
            int r = f2 >> 5;     // 32 float2 per row
            int c2 = f2 & 31;
            int gr = row0 + r;
            if (gr >= BN) gr = BN - 1;
            float2 val = ((const float2*)(X + (size_t)gr * 128 + kk))[c2];
            ((float2*)(xs + r * 66))[c2] = val;
        }
        __syncthreads();
#pragma unroll
        for (int k = 0; k < 64; k++) {
            float xa = xs[(rg * 2) * 66 + k];
            float xb = xs[(rg * 2 + 1) * 66 + k];
            const float4* wr = (const float4*)(Wl + k * 132 + cg * 8);
            float4 w0 = wr[0];
            float4 w1 = wr[1];
            acc[0][0] += xa * w0.x; acc[0][1] += xa * w0.y;
            acc[0][2] += xa * w0.z; acc[0][3] += xa * w0.w;
            acc[0][4] += xa * w1.x; acc[0][5] += xa * w1.y;
            acc[0][6] += xa * w1.z; acc[0][7] += xa * w1.w;
            acc[1][0] += xb * w0.x; acc[1][1] += xb * w0.y;
            acc[1][2] += xb * w0.z; acc[1][3] += xb * w0.w;
            acc[1][4] += xb * w1.x; acc[1][5] += xb * w1.y;
            acc[1][6] += xb * w1.z; acc[1][7] += xb * w1.w;
        }
        __syncthreads();
    }

#pragma unroll
    for (int i = 0; i < 2; i++) {
        int r = row0 + rg * 2 + i;
        if (r >= BN) continue;
        float* op = out + (size_t)r * 128 + cg * 8;
        if (MODE == 0) {
            float4 o0 = make_float4(acc[i][0], acc[i][1], acc[i][2], acc[i][3]);
            float4 o1 = make_float4(acc[i][4], acc[i][5], acc[i][6], acc[i][7]);
            ((float4*)op)[0] = o0;
            ((float4*)op)[1] = o1;
        } else {
            float4 b0 = ((const float4*)(bias + cg * 8))[0];
            float4 b1 = ((const float4*)(bias + cg * 8))[1];
            float4 p0 = ((float4*)op)[0];
            float4 p1 = ((float4*)op)[1];
            p0.x += 0.3f * (acc[i][0] + b0.x); p0.y += 0.3f * (acc[i][1] + b0.y);
            p0.z += 0.3f * (acc[i][2] + b0.z); p0.w += 0.3f * (acc[i][3] + b0.w);
            p1.x += 0.3f * (acc[i][4] + b1.x); p1.y += 0.3f * (acc[i][5] + b1.y);
            p1.z += 0.3f * (acc[i][6] + b1.z); p1.w += 0.3f * (acc[i][7] + b1.w);
            ((float4*)op)[0] = p0;
            ((float4*)op)[1] = p1;
        }
    }
}

// ---------------- aggregation: one wave per node ----------------
// out[n] = gelu( sum_{e: dst=n} nrm_e * XW[src_e] + dinv[n]^2 * XW[n] + bias )

__global__ __launch_bounds__(256) void agg_kernel(const float* __restrict__ XW,
                                                  const float* __restrict__ dinv,
                                                  const int* __restrict__ ptr,
                                                  const int* __restrict__ endp,
                                                  const int* __restrict__ csr_src,
                                                  const float* __restrict__ csr_nrm,
                                                  const float* __restrict__ bias,
                                                  float* __restrict__ out, int BN) {
    int wid = threadIdx.x >> 6;
    int lane = threadIdx.x & 63;
    int n = blockIdx.x * 4 + wid;
    if (n >= BN) return;
    int beg = ptr[n];
    int end = endp[n];
    float2 acc = make_float2(0.0f, 0.0f);
    for (int i = beg; i < end; i++) {
        int s = csr_src[i];
        float nrm = csr_nrm[i];
        float2 v = ((const float2*)(XW + (size_t)s * 128))[lane];
        acc.x += nrm * v.x;
        acc.y += nrm * v.y;
    }
    float dn = dinv[n];
    float sl = dn * dn;
    float2 v = ((const float2*)(XW + (size_t)n * 128))[lane];
    acc.x += sl * v.x;
    acc.y += sl * v.y;
    float2 bb = ((const float2*)bias)[lane];
    float2 o;
    o.x = gelu_exact(acc.x + bb.x);
    o.y = gelu_exact(acc.y + bb.y);
    ((float2*)(out + (size_t)n * 128))[lane] = o;
}

// ---------------- launch ----------------

extern "C" void kernel_launch(void* const* d_in, const int* in_sizes, int n_in,
                              void* d_out, int out_size, void* d_ws, size_t ws_size,
                              hipStream_t stream) {
    const float* x = (const float*)d_in[0];
    const int* ei = (const int*)d_in[1];        // harness passes integers as int32
    const float* w = (const float*)d_in[5];
    const float* W1 = (const float*)d_in[7];
    const float* b1 = (const float*)d_in[8];
    const float* W2 = (const float*)d_in[9];
    const float* b2 = (const float*)d_in[10];
    const float* Wres = (const float*)d_in[11];
    const float* bres = (const float*)d_in[12];

    const int BN = in_sizes[0] / DIM;
    const int E = in_sizes[1] / 2;

    // workspace layout (all 16B aligned); h-buffer lives in d_out to save ws.
    char* p = (char*)d_ws;
    float* A = (float*)p;              p += (size_t)BN * DIM * 4;  // xw buffer (reused layer2)
    float* degf = (float*)p;           p += (size_t)BN * 4;        // deg -> dinv in place
    int* cnt = (int*)p;                p += (size_t)BN * 4;
    int* ptr = (int*)p;                p += (size_t)BN * 4;
    int* cursor = (int*)p;             p += (size_t)BN * 4;        // bump cursors -> end offsets
    int* csr_src = (int*)p;            p += (size_t)E * 4;
    float* csr_nrm = (float*)p;        p += (size_t)E * 4;

    float* Bf = (float*)d_out;         // h buffer; fully overwritten by final agg

    const int* dst32 = ei + E;

    hipMemsetAsync(degf, 0, (size_t)BN * 4, stream);
    hipMemsetAsync(cnt, 0, (size_t)BN * 4, stream);

    int tE = (E + 255) / 256;
    int tN = (BN + 255) / 256;

    deg_cnt_kernel<<<tE, 256, 0, stream>>>(dst32, w, degf, cnt, E);
    dinv_kernel<<<tN, 256, 0, stream>>>(degf, BN);
    scan_kernel<<<1, 256, 0, stream>>>(cnt, ptr, cursor, BN);
    fill_kernel<<<tE, 256, 0, stream>>>(ei, w, degf, cursor, csr_src, csr_nrm, E);

    int gemmBlocks = (BN + 31) / 32;
    int aggBlocks = (BN + 3) / 4;

    // layer 1: A = x@W1 ; Bf = gelu(agg(A) + b1) ; Bf += 0.3*(x@Wres + bres)
    gemm128_kernel<0><<<gemmBlocks, 256, 0, stream>>>(x, W1, nullptr, A, BN);
    agg_kernel<<<aggBlocks, 256, 0, stream>>>(A, degf, ptr, cursor, csr_src, csr_nrm, b1, Bf, BN);
    gemm128_kernel<1><<<gemmBlocks, 256, 0, stream>>>(x, Wres, bres, Bf, BN);

    // layer 2: A = Bf@W2 ; out = gelu(agg(A) + b2)
    gemm128_kernel<0><<<gemmBlocks, 256, 0, stream>>>(Bf, W2, nullptr, A, BN);
    agg_kernel<<<aggBlocks, 256, 0, stream>>>(A, degf, ptr, cursor, csr_src, csr_nrm, b2, (float*)d_out, BN);
}

// Round 4
// 940.192 us; speedup vs baseline: 1.1506x; 1.1506x over previous
//
#include <hip/hip_runtime.h>
#include <math.h>

#define DIM 128
#define SCAN_CHUNK 4096  // 256 threads * 16 elems

__device__ __forceinline__ float gelu_exact(float v) {
    return 0.5f * v * (1.0f + erff(v * 0.70710678118654752f));
}

// ---------------- graph build ----------------

__global__ void deg_cnt_kernel(const int* __restrict__ dst,
                               const float* __restrict__ w,
                               float* __restrict__ degf, int* __restrict__ cnt, int E) {
    int e = blockIdx.x * blockDim.x + threadIdx.x;
    if (e >= E) return;
    int d = dst[e];
    atomicAdd(&degf[d], w[e]);
    atomicAdd(&cnt[d], 1);
}

__global__ void dinv_kernel(float* __restrict__ degf, int BN) {
    int n = blockIdx.x * blockDim.x + threadIdx.x;
    if (n >= BN) return;
    degf[n] = rsqrtf(degf[n] + 1.0f);
}

// ---- hierarchical scan: A (block reduce) -> B (scan partials) -> C (local scan + offset)

__global__ __launch_bounds__(256) void scanA_kernel(const int* __restrict__ cnt,
                                                    int* __restrict__ partials, int BN) {
    int tid = threadIdx.x;
    int base = blockIdx.x * SCAN_CHUNK;
    int sum = 0;
#pragma unroll
    for (int i = 0; i < 16; i++) {
        int ii = base + i * 256 + tid;
        if (ii < BN) sum += cnt[ii];
    }
    __shared__ int lds[4];
#pragma unroll
    for (int off = 32; off; off >>= 1) sum += __shfl_down(sum, off, 64);
    if ((tid & 63) == 0) lds[tid >> 6] = sum;
    __syncthreads();
    if (tid == 0) partials[blockIdx.x] = lds[0] + lds[1] + lds[2] + lds[3];
}

__global__ __launch_bounds__(256) void scanB_kernel(int* __restrict__ partials, int nblk) {
    __shared__ int lds[256];
    int tid = threadIdx.x;
    int v = (tid < nblk) ? partials[tid] : 0;
    lds[tid] = v;
    __syncthreads();
#pragma unroll
    for (int off = 1; off < 256; off <<= 1) {
        int t = (tid >= off) ? lds[tid - off] : 0;
        __syncthreads();
        lds[tid] += t;
        __syncthreads();
    }
    if (tid < nblk) partials[tid] = lds[tid] - v;  // exclusive
}

__global__ __launch_bounds__(256) void scanC_kernel(const int* __restrict__ cnt,
                                                    const int* __restrict__ partials,
                                                    int* __restrict__ ptr,
                                                    int* __restrict__ cursor, int BN) {
    __shared__ int lds[256];
    int tid = threadIdx.x;
    int base = blockIdx.x * SCAN_CHUNK;
    int idx0 = base + tid * 16;
    int v[16];
    int tsum = 0;
#pragma unroll
    for (int j = 0; j < 16; j++) {
        int ii = idx0 + j;
        v[j] = (ii < BN) ? cnt[ii] : 0;
        tsum += v[j];
    }
    lds[tid] = tsum;
    __syncthreads();
#pragma unroll
    for (int off = 1; off < 256; off <<= 1) {
        int t = (tid >= off) ? lds[tid - off] : 0;
        __syncthreads();
        lds[tid] += t;
        __syncthreads();
    }
    int excl = lds[tid] - tsum + partials[blockIdx.x];
#pragma unroll
    for (int j = 0; j < 16; j++) {
        int ii = idx0 + j;
        if (ii < BN) { ptr[ii] = excl; cursor[ii] = excl; }
        excl += v[j];
    }
}

__global__ void fill_kernel(const int* __restrict__ ei, const float* __restrict__ w,
                            const float* __restrict__ dinv, int* __restrict__ cursor,
                            int* __restrict__ csr_src, float* __restrict__ csr_nrm, int E) {
    int e = blockIdx.x * blockDim.x + threadIdx.x;
    if (e >= E) return;
    int s = ei[e];
    int d = ei[(size_t)E + e];
    int pos = atomicAdd(&cursor[d], 1);
    csr_src[pos] = s;
    csr_nrm[pos] = dinv[s] * w[e] * dinv[d];
}

// ---------------- GEMM: [BN,128] @ [128,128], fp32 vector ALU ----------------
// MODE 0: out = X@W            MODE 1: out += 0.3f*(X@W + bias)

template <int MODE>
__global__ __launch_bounds__(256) void gemm128_kernel(const float* __restrict__ X,
                                                      const float* __restrict__ W,
                                                      const float* __restrict__ bias,
                                                      float* __restrict__ out, int BN) {
    __shared__ float Wl[64 * 132];  // K-chunk 64 x 128, row pad to 132 floats
    __shared__ float xs[32 * 66];   // 32 rows x 64-col chunk, pad 66

    int tid = threadIdx.x;
    int cg = tid & 15;   // column group: 8 consecutive cols
    int rg = tid >> 4;   // row group: 2 consecutive rows
    int row0 = blockIdx.x * 32;

    float acc[2][8];
#pragma unroll
    for (int i = 0; i < 2; i++)
#pragma unroll
        for (int j = 0; j < 8; j++) acc[i][j] = 0.0f;

    for (int kk = 0; kk < 128; kk += 64) {
        // stage W chunk: 64x128 floats = 2048 float4, 8 per thread
#pragma unroll
        for (int i = 0; i < 8; i++) {
            int f4 = tid + i * 256;
            int r = f4 >> 5;     // 32 float4 per row
            int c4 = f4 & 31;
            float4 val = ((const float4*)(W + (size_t)(kk + r) * 128))[c4];
            ((float4*)(Wl + r * 132))[c4] = val;
        }
        // stage x chunk: 32x64 floats = 1024 float2, 4 per thread
#pragma unroll
        for (int i = 0; i < 4; i++) {
            int f2 = tid + i * 256;
            int r = f2 >> 5;     // 32 float2 per row
            int c2 = f2 & 31;
            int gr = row0 + r;
            if (gr >= BN) gr = BN - 1;
            float2 val = ((const float2*)(X + (size_t)gr * 128 + kk))[c2];
            ((float2*)(xs + r * 66))[c2] = val;
        }
        __syncthreads();
#pragma unroll
        for (int k = 0; k < 64; k++) {
            float xa = xs[(rg * 2) * 66 + k];
            float xb = xs[(rg * 2 + 1) * 66 + k];
            const float4* wr = (const float4*)(Wl + k * 132 + cg * 8);
            float4 w0 = wr[0];
            float4 w1 = wr[1];
            acc[0][0] += xa * w0.x; acc[0][1] += xa * w0.y;
            acc[0][2] += xa * w0.z; acc[0][3] += xa * w0.w;
            acc[0][4] += xa * w1.x; acc[0][5] += xa * w1.y;
            acc[0][6] += xa * w1.z; acc[0][7] += xa * w1.w;
            acc[1][0] += xb * w0.x; acc[1][1] += xb * w0.y;
            acc[1][2] += xb * w0.z; acc[1][3] += xb * w0.w;
            acc[1][4] += xb * w1.x; acc[1][5] += xb * w1.y;
            acc[1][6] += xb * w1.z; acc[1][7] += xb * w1.w;
        }
        __syncthreads();
    }

#pragma unroll
    for (int i = 0; i < 2; i++) {
        int r = row0 + rg * 2 + i;
        if (r >= BN) continue;
        float* op = out + (size_t)r * 128 + cg * 8;
        if (MODE == 0) {
            float4 o0 = make_float4(acc[i][0], acc[i][1], acc[i][2], acc[i][3]);
            float4 o1 = make_float4(acc[i][4], acc[i][5], acc[i][6], acc[i][7]);
            ((float4*)op)[0] = o0;
            ((float4*)op)[1] = o1;
        } else {
            float4 b0 = ((const float4*)(bias + cg * 8))[0];
            float4 b1 = ((const float4*)(bias + cg * 8))[1];
            float4 p0 = ((float4*)op)[0];
            float4 p1 = ((float4*)op)[1];
            p0.x += 0.3f * (acc[i][0] + b0.x); p0.y += 0.3f * (acc[i][1] + b0.y);
            p0.z += 0.3f * (acc[i][2] + b0.z); p0.w += 0.3f * (acc[i][3] + b0.w);
            p1.x += 0.3f * (acc[i][4] + b1.x); p1.y += 0.3f * (acc[i][5] + b1.y);
            p1.z += 0.3f * (acc[i][6] + b1.z); p1.w += 0.3f * (acc[i][7] + b1.w);
            ((float4*)op)[0] = p0;
            ((float4*)op)[1] = p1;
        }
    }
}

// ---------------- aggregation: one wave per node ----------------
// out[n] = gelu( sum_{e: dst=n} nrm_e * XW[src_e] + dinv[n]^2 * XW[n] + bias )

__global__ __launch_bounds__(256) void agg_kernel(const float* __restrict__ XW,
                                                  const float* __restrict__ dinv,
                                                  const int* __restrict__ ptr,
                                                  const int* __restrict__ endp,
                                                  const int* __restrict__ csr_src,
                                                  const float* __restrict__ csr_nrm,
                                                  const float* __restrict__ bias,
                                                  float* __restrict__ out, int BN) {
    int wid = threadIdx.x >> 6;
    int lane = threadIdx.x & 63;
    int n = blockIdx.x * 4 + wid;
    if (n >= BN) return;
    int beg = ptr[n];
    int end = endp[n];
    float2 acc = make_float2(0.0f, 0.0f);
    for (int i = beg; i < end; i++) {
        int s = csr_src[i];
        float nrm = csr_nrm[i];
        float2 v = ((const float2*)(XW + (size_t)s * 128))[lane];
        acc.x += nrm * v.x;
        acc.y += nrm * v.y;
    }
    float dn = dinv[n];
    float sl = dn * dn;
    float2 v = ((const float2*)(XW + (size_t)n * 128))[lane];
    acc.x += sl * v.x;
    acc.y += sl * v.y;
    float2 bb = ((const float2*)bias)[lane];
    float2 o;
    o.x = gelu_exact(acc.x + bb.x);
    o.y = gelu_exact(acc.y + bb.y);
    ((float2*)(out + (size_t)n * 128))[lane] = o;
}

// ---------------- launch ----------------

extern "C" void kernel_launch(void* const* d_in, const int* in_sizes, int n_in,
                              void* d_out, int out_size, void* d_ws, size_t ws_size,
                              hipStream_t stream) {
    const float* x = (const float*)d_in[0];
    const int* ei = (const int*)d_in[1];        // harness passes integers as int32
    const float* w = (const float*)d_in[5];
    const float* W1 = (const float*)d_in[7];
    const float* b1 = (const float*)d_in[8];
    const float* W2 = (const float*)d_in[9];
    const float* b2 = (const float*)d_in[10];
    const float* Wres = (const float*)d_in[11];
    const float* bres = (const float*)d_in[12];

    const int BN = in_sizes[0] / DIM;
    const int E = in_sizes[1] / 2;
    const int NBLK = (BN + SCAN_CHUNK - 1) / SCAN_CHUNK;

    // workspace layout (all 16B aligned); h-buffer lives in d_out to save ws.
    char* p = (char*)d_ws;
    float* A = (float*)p;              p += (size_t)BN * DIM * 4;  // xw buffer (reused layer2)
    float* degf = (float*)p;           p += (size_t)BN * 4;        // deg -> dinv in place
    int* cnt = (int*)p;                p += (size_t)BN * 4;
    int* ptr = (int*)p;                p += (size_t)BN * 4;
    int* cursor = (int*)p;             p += (size_t)BN * 4;        // bump cursors -> end offsets
    int* partials = (int*)p;           p += 1024;                  // scan partials (<=256 blocks)
    int* csr_src = (int*)p;            p += (size_t)E * 4;
    float* csr_nrm = (float*)p;        p += (size_t)E * 4;

    float* Bf = (float*)d_out;         // h buffer; fully overwritten by final agg

    const int* dst32 = ei + E;

    hipMemsetAsync(degf, 0, (size_t)BN * 4, stream);
    hipMemsetAsync(cnt, 0, (size_t)BN * 4, stream);

    int tE = (E + 255) / 256;
    int tN = (BN + 255) / 256;

    deg_cnt_kernel<<<tE, 256, 0, stream>>>(dst32, w, degf, cnt, E);
    dinv_kernel<<<tN, 256, 0, stream>>>(degf, BN);
    scanA_kernel<<<NBLK, 256, 0, stream>>>(cnt, partials, BN);
    scanB_kernel<<<1, 256, 0, stream>>>(partials, NBLK);
    scanC_kernel<<<NBLK, 256, 0, stream>>>(cnt, partials, ptr, cursor, BN);
    fill_kernel<<<tE, 256, 0, stream>>>(ei, w, degf, cursor, csr_src, csr_nrm, E);

    int gemmBlocks = (BN + 31) / 32;
    int aggBlocks = (BN + 3) / 4;

    // layer 1: A = x@W1 ; Bf = gelu(agg(A) + b1) ; Bf += 0.3*(x@Wres + bres)
    gemm128_kernel<0><<<gemmBlocks, 256, 0, stream>>>(x, W1, nullptr, A, BN);
    agg_kernel<<<aggBlocks, 256, 0, stream>>>(A, degf, ptr, cursor, csr_src, csr_nrm, b1, Bf, BN);
    gemm128_kernel<1><<<gemmBlocks, 256, 0, stream>>>(x, Wres, bres, Bf, BN);

    // layer 2: A = Bf@W2 ; out = gelu(agg(A) + b2)
    gemm128_kernel<0><<<gemmBlocks, 256, 0, stream>>>(Bf, W2, nullptr, A, BN);
    agg_kernel<<<aggBlocks, 256, 0, stream>>>(A, degf, ptr, cursor, csr_src, csr_nrm, b2, (float*)d_out, BN);
}

// Round 5
// 714.199 us; speedup vs baseline: 1.5147x; 1.3164x over previous
//
#include <hip/hip_runtime.h>
#include <math.h>

#define DIM 128
#define SCAN_CHUNK 4096  // 256 threads * 16 elems

typedef __attribute__((ext_vector_type(8))) short short8;
typedef __attribute__((ext_vector_type(4))) float f32x4;

__device__ __forceinline__ float gelu_exact(float v) {
    return 0.5f * v * (1.0f + erff(v * 0.70710678118654752f));
}

// round-to-nearest-even fp32 -> bf16 bits (finite inputs)
__device__ __forceinline__ unsigned short f2bf(float f) {
    unsigned int u = __float_as_uint(f);
    return (unsigned short)((u + 0x7FFFu + ((u >> 16) & 1u)) >> 16);
}
__device__ __forceinline__ float bf_lo(unsigned int v) { return __uint_as_float(v << 16); }
__device__ __forceinline__ float bf_hi(unsigned int v) { return __uint_as_float(v & 0xFFFF0000u); }

// ---------------- graph build ----------------

__global__ void deg_cnt_kernel(const int* __restrict__ dst,
                               const float* __restrict__ w,
                               float* __restrict__ degf, int* __restrict__ cnt, int E) {
    int e = blockIdx.x * blockDim.x + threadIdx.x;
    if (e >= E) return;
    int d = dst[e];
    atomicAdd(&degf[d], w[e]);
    atomicAdd(&cnt[d], 1);
}

__global__ void dinv_kernel(float* __restrict__ degf, int BN) {
    int n = blockIdx.x * blockDim.x + threadIdx.x;
    if (n >= BN) return;
    degf[n] = rsqrtf(degf[n] + 1.0f);
}

__global__ __launch_bounds__(256) void scanA_kernel(const int* __restrict__ cnt,
                                                    int* __restrict__ partials, int BN) {
    int tid = threadIdx.x;
    int base = blockIdx.x * SCAN_CHUNK;
    int sum = 0;
#pragma unroll
    for (int i = 0; i < 16; i++) {
        int ii = base + i * 256 + tid;
        if (ii < BN) sum += cnt[ii];
    }
    __shared__ int lds[4];
#pragma unroll
    for (int off = 32; off; off >>= 1) sum += __shfl_down(sum, off, 64);
    if ((tid & 63) == 0) lds[tid >> 6] = sum;
    __syncthreads();
    if (tid == 0) partials[blockIdx.x] = lds[0] + lds[1] + lds[2] + lds[3];
}

__global__ __launch_bounds__(256) void scanB_kernel(int* __restrict__ partials, int nblk) {
    __shared__ int lds[256];
    int tid = threadIdx.x;
    int v = (tid < nblk) ? partials[tid] : 0;
    lds[tid] = v;
    __syncthreads();
#pragma unroll
    for (int off = 1; off < 256; off <<= 1) {
        int t = (tid >= off) ? lds[tid - off] : 0;
        __syncthreads();
        lds[tid] += t;
        __syncthreads();
    }
    if (tid < nblk) partials[tid] = lds[tid] - v;  // exclusive
}

__global__ __launch_bounds__(256) void scanC_kernel(const int* __restrict__ cnt,
                                                    const int* __restrict__ partials,
                                                    int* __restrict__ ptr,
                                                    int* __restrict__ cursor, int BN) {
    __shared__ int lds[256];
    int tid = threadIdx.x;
    int base = blockIdx.x * SCAN_CHUNK;
    int idx0 = base + tid * 16;
    int v[16];
    int tsum = 0;
#pragma unroll
    for (int j = 0; j < 16; j++) {
        int ii = idx0 + j;
        v[j] = (ii < BN) ? cnt[ii] : 0;
        tsum += v[j];
    }
    lds[tid] = tsum;
    __syncthreads();
#pragma unroll
    for (int off = 1; off < 256; off <<= 1) {
        int t = (tid >= off) ? lds[tid - off] : 0;
        __syncthreads();
        lds[tid] += t;
        __syncthreads();
    }
    int excl = lds[tid] - tsum + partials[blockIdx.x];
#pragma unroll
    for (int j = 0; j < 16; j++) {
        int ii = idx0 + j;
        if (ii < BN) { ptr[ii] = excl; cursor[ii] = excl; }
        excl += v[j];
    }
}

__global__ void fill_kernel(const int* __restrict__ ei, const float* __restrict__ w,
                            const float* __restrict__ dinv, int* __restrict__ cursor,
                            int* __restrict__ csr_src, float* __restrict__ csr_nrm, int E) {
    int e = blockIdx.x * blockDim.x + threadIdx.x;
    if (e >= E) return;
    int s = ei[e];
    int d = ei[(size_t)E + e];
    int pos = atomicAdd(&cursor[d], 1);
    csr_src[pos] = s;
    csr_nrm[pos] = dinv[s] * w[e] * dinv[d];
}

// ---------------- weight transpose + bf16: Wt[c][k] = bf16(W[k][c]) ----------------

__global__ __launch_bounds__(256) void wt_kernel(const float* __restrict__ W,
                                                 unsigned short* __restrict__ Wt) {
    int idx = blockIdx.x * 256 + threadIdx.x;  // idx = r*128 + c
    int r = idx >> 7, c = idx & 127;
    Wt[c * 128 + r] = f2bf(W[idx]);
}

// ---------------- MFMA GEMM: [BN,128] @ [128,128] via bf16 16x16x32 ----------------
// MODE 0: outb = bf16(X @ W)        MODE 1: Bf += 0.3f*(X@W + bias)
// No LDS: A rows read fp32-direct (converted in-reg), B-frags read from
// pre-transposed bf16 Wt (32 KB, L2-resident).
// Fragment layouts (guide-verified): A row=l&15, k=(l>>4)*8+j;
// C/D col=l&15, row=(l>>4)*4+reg.

template <int MODE>
__global__ __launch_bounds__(256) void mfma_gemm_kernel(const float* __restrict__ X,
                                                        const unsigned short* __restrict__ Wt,
                                                        const float* __restrict__ bias,
                                                        unsigned short* __restrict__ outb,
                                                        float* __restrict__ Bf, int BN) {
    int tid = threadIdx.x;
    int w = tid >> 6, l = tid & 63;
    int l15 = l & 15, kg = l >> 4;
    int row0 = blockIdx.x * 64 + w * 16;

    int rowA = row0 + l15;
    if (rowA > BN - 1) rowA = BN - 1;
    const float* ap = X + (size_t)rowA * 128 + kg * 8;

    f32x4 acc[8];
#pragma unroll
    for (int nt = 0; nt < 8; nt++) acc[nt] = (f32x4){0.f, 0.f, 0.f, 0.f};

#pragma unroll
    for (int ks = 0; ks < 4; ks++) {
        float4 a0 = *(const float4*)(ap + ks * 32);
        float4 a1 = *(const float4*)(ap + ks * 32 + 4);
        short8 aF;
        aF[0] = (short)f2bf(a0.x); aF[1] = (short)f2bf(a0.y);
        aF[2] = (short)f2bf(a0.z); aF[3] = (short)f2bf(a0.w);
        aF[4] = (short)f2bf(a1.x); aF[5] = (short)f2bf(a1.y);
        aF[6] = (short)f2bf(a1.z); aF[7] = (short)f2bf(a1.w);
#pragma unroll
        for (int nt = 0; nt < 8; nt++) {
            int colB = nt * 16 + l15;
            uint4 bu = *(const uint4*)(Wt + (size_t)colB * 128 + ks * 32 + kg * 8);
            short8 bF = __builtin_bit_cast(short8, bu);
            acc[nt] = __builtin_amdgcn_mfma_f32_16x16x32_bf16(aF, bF, acc[nt], 0, 0, 0);
        }
    }

#pragma unroll
    for (int nt = 0; nt < 8; nt++) {
        int col = nt * 16 + l15;
#pragma unroll
        for (int r = 0; r < 4; r++) {
            int row = row0 + kg * 4 + r;
            if (row >= BN) continue;
            size_t idx = (size_t)row * 128 + col;
            if (MODE == 0) {
                outb[idx] = f2bf(acc[nt][r]);
            } else {
                Bf[idx] += 0.3f * (acc[nt][r] + bias[col]);
            }
        }
    }
}

// ---------------- aggregation: one wave per node, bf16 gather ----------------
// out[n] = gelu( sum_{e: dst=n} nrm_e * XWb[src_e] + dinv[n]^2 * XWb[n] + bias )

__global__ __launch_bounds__(256) void agg_kernel(const unsigned short* __restrict__ XWb,
                                                  const float* __restrict__ dinv,
                                                  const int* __restrict__ ptr,
                                                  const int* __restrict__ endp,
                                                  const int* __restrict__ csr_src,
                                                  const float* __restrict__ csr_nrm,
                                                  const float* __restrict__ bias,
                                                  float* __restrict__ out, int BN) {
    int wid = threadIdx.x >> 6;
    int lane = threadIdx.x & 63;
    int n = blockIdx.x * 4 + wid;
    if (n >= BN) return;
    int beg = ptr[n];
    int end = endp[n];
    float a0 = 0.f, a1 = 0.f, a2 = 0.f, a3 = 0.f;  // two independent acc pairs (MLP)
    int i = beg;
    for (; i + 1 < end; i += 2) {
        int s0 = csr_src[i], s1 = csr_src[i + 1];
        float n0 = csr_nrm[i], n1 = csr_nrm[i + 1];
        unsigned int v0 = ((const unsigned int*)(XWb + (size_t)s0 * 128))[lane];
        unsigned int v1 = ((const unsigned int*)(XWb + (size_t)s1 * 128))[lane];
        a0 += n0 * bf_lo(v0); a1 += n0 * bf_hi(v0);
        a2 += n1 * bf_lo(v1); a3 += n1 * bf_hi(v1);
    }
    if (i < end) {
        int s0 = csr_src[i];
        float n0 = csr_nrm[i];
        unsigned int v0 = ((const unsigned int*)(XWb + (size_t)s0 * 128))[lane];
        a0 += n0 * bf_lo(v0); a1 += n0 * bf_hi(v0);
    }
    float dn = dinv[n];
    float sl = dn * dn;
    unsigned int vs = ((const unsigned int*)(XWb + (size_t)n * 128))[lane];
    a0 += sl * bf_lo(vs) + a2;
    a1 += sl * bf_hi(vs) + a3;
    float2 bb = ((const float2*)bias)[lane];
    float2 o;
    o.x = gelu_exact(a0 + bb.x);
    o.y = gelu_exact(a1 + bb.y);
    ((float2*)(out + (size_t)n * 128))[lane] = o;
}

// ---------------- launch ----------------

extern "C" void kernel_launch(void* const* d_in, const int* in_sizes, int n_in,
                              void* d_out, int out_size, void* d_ws, size_t ws_size,
                              hipStream_t stream) {
    const float* x = (const float*)d_in[0];
    const int* ei = (const int*)d_in[1];        // harness passes integers as int32
    const float* w = (const float*)d_in[5];
    const float* W1 = (const float*)d_in[7];
    const float* b1 = (const float*)d_in[8];
    const float* W2 = (const float*)d_in[9];
    const float* b2 = (const float*)d_in[10];
    const float* Wres = (const float*)d_in[11];
    const float* bres = (const float*)d_in[12];

    const int BN = in_sizes[0] / DIM;
    const int E = in_sizes[1] / 2;
    const int NBLK = (BN + SCAN_CHUNK - 1) / SCAN_CHUNK;

    // workspace layout (16B aligned); h-buffer lives in d_out.
    char* p = (char*)d_ws;
    unsigned short* Ab = (unsigned short*)p;  p += (size_t)BN * DIM * 2;  // bf16 XW (reused layer2)
    float* degf = (float*)p;           p += (size_t)BN * 4;
    int* cnt = (int*)p;                p += (size_t)BN * 4;
    int* ptr = (int*)p;                p += (size_t)BN * 4;
    int* cursor = (int*)p;             p += (size_t)BN * 4;
    int* partials = (int*)p;           p += 1024;
    unsigned short* Wt1 = (unsigned short*)p;   p += 128 * 128 * 2;
    unsigned short* Wtr = (unsigned short*)p;   p += 128 * 128 * 2;
    unsigned short* Wt2 = (unsigned short*)p;   p += 128 * 128 * 2;
    int* csr_src = (int*)p;            p += (size_t)E * 4;
    float* csr_nrm = (float*)p;        p += (size_t)E * 4;

    float* Bf = (float*)d_out;         // h buffer; fully overwritten by final agg

    const int* dst32 = ei + E;

    hipMemsetAsync(degf, 0, (size_t)BN * 4, stream);
    hipMemsetAsync(cnt, 0, (size_t)BN * 4, stream);

    int tE = (E + 255) / 256;
    int tN = (BN + 255) / 256;

    deg_cnt_kernel<<<tE, 256, 0, stream>>>(dst32, w, degf, cnt, E);
    dinv_kernel<<<tN, 256, 0, stream>>>(degf, BN);
    scanA_kernel<<<NBLK, 256, 0, stream>>>(cnt, partials, BN);
    scanB_kernel<<<1, 256, 0, stream>>>(partials, NBLK);
    scanC_kernel<<<NBLK, 256, 0, stream>>>(cnt, partials, ptr, cursor, BN);
    fill_kernel<<<tE, 256, 0, stream>>>(ei, w, degf, cursor, csr_src, csr_nrm, E);

    wt_kernel<<<64, 256, 0, stream>>>(W1, Wt1);
    wt_kernel<<<64, 256, 0, stream>>>(Wres, Wtr);
    wt_kernel<<<64, 256, 0, stream>>>(W2, Wt2);

    int gemmBlocks = (BN + 63) / 64;
    int aggBlocks = (BN + 3) / 4;

    // layer 1: Ab = bf16(x@W1) ; Bf = gelu(agg(Ab) + b1) ; Bf += 0.3*(x@Wres + bres)
    mfma_gemm_kernel<0><<<gemmBlocks, 256, 0, stream>>>(x, Wt1, nullptr, Ab, nullptr, BN);
    agg_kernel<<<aggBlocks, 256, 0, stream>>>(Ab, degf, ptr, cursor, csr_src, csr_nrm, b1, Bf, BN);
    mfma_gemm_kernel<1><<<gemmBlocks, 256, 0, stream>>>(x, Wtr, bres, nullptr, Bf, BN);

    // layer 2: Ab = bf16(Bf@W2) ; out = gelu(agg(Ab) + b2)
    mfma_gemm_kernel<0><<<gemmBlocks, 256, 0, stream>>>(Bf, Wt2, nullptr, Ab, nullptr, BN);
    agg_kernel<<<aggBlocks, 256, 0, stream>>>(Ab, degf, ptr, cursor, csr_src, csr_nrm, b2, (float*)d_out, BN);
}

// Round 6
// 519.621 us; speedup vs baseline: 2.0818x; 1.3745x over previous
//
#include <hip/hip_runtime.h>
#include <math.h>

#define DIM 128
#define SCAN_CHUNK 4096  // 256 threads * 16 elems

typedef __attribute__((ext_vector_type(8))) short short8;
typedef __attribute__((ext_vector_type(4))) float f32x4;

__device__ __forceinline__ float gelu_exact(float v) {
    return 0.5f * v * (1.0f + erff(v * 0.70710678118654752f));
}

// round-to-nearest-even fp32 -> bf16 bits (finite inputs)
__device__ __forceinline__ unsigned short f2bf(float f) {
    unsigned int u = __float_as_uint(f);
    return (unsigned short)((u + 0x7FFFu + ((u >> 16) & 1u)) >> 16);
}
__device__ __forceinline__ float bf_lo(unsigned int v) { return __uint_as_float(v << 16); }
__device__ __forceinline__ float bf_hi(unsigned int v) { return __uint_as_float(v & 0xFFFF0000u); }

// ---------------- graph build ----------------
// packed[d]: high 32 = edge count, low 32 = sum(w) in 2^26 fixed point.
// One 64-bit atomic per edge; returned old high word = rank within segment.

__global__ void deg_cnt_kernel(const int* __restrict__ dst,
                               const float* __restrict__ w,
                               unsigned long long* __restrict__ packed,
                               int* __restrict__ rank, int E) {
    int e = blockIdx.x * blockDim.x + threadIdx.x;
    if (e >= E) return;
    int d = dst[e];
    unsigned long long inc =
        (1ull << 32) | (unsigned long long)(unsigned int)(w[e] * 67108864.0f);
    unsigned long long old = atomicAdd(&packed[d], inc);
    rank[e] = (int)(old >> 32);
}

__global__ void dinv_kernel(const unsigned long long* __restrict__ packed,
                            float* __restrict__ dinvf, int* __restrict__ cnt, int BN) {
    int n = blockIdx.x * blockDim.x + threadIdx.x;
    if (n >= BN) return;
    unsigned long long v = packed[n];
    cnt[n] = (int)(v >> 32);
    float sum = (float)(unsigned int)(v & 0xFFFFFFFFu) * (1.0f / 67108864.0f);
    dinvf[n] = rsqrtf(sum + 1.0f);
}

__global__ __launch_bounds__(256) void scanA_kernel(const int* __restrict__ cnt,
                                                    int* __restrict__ partials, int BN) {
    int tid = threadIdx.x;
    int base = blockIdx.x * SCAN_CHUNK;
    int sum = 0;
#pragma unroll
    for (int i = 0; i < 16; i++) {
        int ii = base + i * 256 + tid;
        if (ii < BN) sum += cnt[ii];
    }
    __shared__ int lds[4];
#pragma unroll
    for (int off = 32; off; off >>= 1) sum += __shfl_down(sum, off, 64);
    if ((tid & 63) == 0) lds[tid >> 6] = sum;
    __syncthreads();
    if (tid == 0) partials[blockIdx.x] = lds[0] + lds[1] + lds[2] + lds[3];
}

__global__ __launch_bounds__(256) void scanB_kernel(int* __restrict__ partials, int nblk) {
    __shared__ int lds[256];
    int tid = threadIdx.x;
    int v = (tid < nblk) ? partials[tid] : 0;
    lds[tid] = v;
    __syncthreads();
#pragma unroll
    for (int off = 1; off < 256; off <<= 1) {
        int t = (tid >= off) ? lds[tid - off] : 0;
        __syncthreads();
        lds[tid] += t;
        __syncthreads();
    }
    if (tid < nblk) partials[tid] = lds[tid] - v;  // exclusive
}

__global__ __launch_bounds__(256) void scanC_kernel(const int* __restrict__ cnt,
                                                    const int* __restrict__ partials,
                                                    int* __restrict__ ptr, int BN) {
    __shared__ int lds[256];
    int tid = threadIdx.x;
    int base = blockIdx.x * SCAN_CHUNK;
    int idx0 = base + tid * 16;
    int v[16];
    int tsum = 0;
#pragma unroll
    for (int j = 0; j < 16; j++) {
        int ii = idx0 + j;
        v[j] = (ii < BN) ? cnt[ii] : 0;
        tsum += v[j];
    }
    lds[tid] = tsum;
    __syncthreads();
#pragma unroll
    for (int off = 1; off < 256; off <<= 1) {
        int t = (tid >= off) ? lds[tid - off] : 0;
        __syncthreads();
        lds[tid] += t;
        __syncthreads();
    }
    int excl = lds[tid] - tsum + partials[blockIdx.x];
#pragma unroll
    for (int j = 0; j < 16; j++) {
        int ii = idx0 + j;
        if (ii < BN) ptr[ii] = excl;
        excl += v[j];
    }
}

// atomic-free fill: pos = ptr[d] + rank[e]; one packed int2 {src, nrm} per edge
__global__ void fill_kernel(const int* __restrict__ ei, const float* __restrict__ w,
                            const int* __restrict__ rank, const int* __restrict__ ptr,
                            const float* __restrict__ dinvf,
                            int2* __restrict__ csr, int E) {
    int e = blockIdx.x * blockDim.x + threadIdx.x;
    if (e >= E) return;
    int s = ei[e];
    int d = ei[(size_t)E + e];
    int pos = ptr[d] + rank[e];
    float nrm = dinvf[s] * w[e] * dinvf[d];
    csr[pos] = make_int2(s, __float_as_int(nrm));
}

// ---------------- weight transpose + bf16: Wt[c][k] = bf16(W[k][c]) ----------------

__global__ __launch_bounds__(256) void wt_kernel(const float* __restrict__ W,
                                                 unsigned short* __restrict__ Wt) {
    int idx = blockIdx.x * 256 + threadIdx.x;  // idx = r*128 + c
    int r = idx >> 7, c = idx & 127;
    Wt[c * 128 + r] = f2bf(W[idx]);
}

// ---------------- MFMA GEMM: [BN,128] @ [128,128] via bf16 16x16x32 ----------------
// MODE 0: outb = bf16(X @ W)        MODE 1: Bf += 0.3f*(X@W + bias)

template <int MODE>
__global__ __launch_bounds__(256) void mfma_gemm_kernel(const float* __restrict__ X,
                                                        const unsigned short* __restrict__ Wt,
                                                        const float* __restrict__ bias,
                                                        unsigned short* __restrict__ outb,
                                                        float* __restrict__ Bf, int BN) {
    int tid = threadIdx.x;
    int w = tid >> 6, l = tid & 63;
    int l15 = l & 15, kg = l >> 4;
    int row0 = blockIdx.x * 64 + w * 16;

    int rowA = row0 + l15;
    if (rowA > BN - 1) rowA = BN - 1;
    const float* ap = X + (size_t)rowA * 128 + kg * 8;

    f32x4 acc[8];
#pragma unroll
    for (int nt = 0; nt < 8; nt++) acc[nt] = (f32x4){0.f, 0.f, 0.f, 0.f};

#pragma unroll
    for (int ks = 0; ks < 4; ks++) {
        float4 a0 = *(const float4*)(ap + ks * 32);
        float4 a1 = *(const float4*)(ap + ks * 32 + 4);
        short8 aF;
        aF[0] = (short)f2bf(a0.x); aF[1] = (short)f2bf(a0.y);
        aF[2] = (short)f2bf(a0.z); aF[3] = (short)f2bf(a0.w);
        aF[4] = (short)f2bf(a1.x); aF[5] = (short)f2bf(a1.y);
        aF[6] = (short)f2bf(a1.z); aF[7] = (short)f2bf(a1.w);
#pragma unroll
        for (int nt = 0; nt < 8; nt++) {
            int colB = nt * 16 + l15;
            uint4 bu = *(const uint4*)(Wt + (size_t)colB * 128 + ks * 32 + kg * 8);
            short8 bF = __builtin_bit_cast(short8, bu);
            acc[nt] = __builtin_amdgcn_mfma_f32_16x16x32_bf16(aF, bF, acc[nt], 0, 0, 0);
        }
    }

#pragma unroll
    for (int nt = 0; nt < 8; nt++) {
        int col = nt * 16 + l15;
#pragma unroll
        for (int r = 0; r < 4; r++) {
            int row = row0 + kg * 4 + r;
            if (row >= BN) continue;
            size_t idx = (size_t)row * 128 + col;
            if (MODE == 0) {
                outb[idx] = f2bf(acc[nt][r]);
            } else {
                Bf[idx] += 0.3f * (acc[nt][r] + bias[col]);
            }
        }
    }
}

// ---------------- aggregation: half-wave (32 lanes) per node, bf16 gather ----------------
// Each of 32 lanes owns 4 features (uint2 = 4 bf16). 8 nodes per 256-thread block.

__global__ __launch_bounds__(256) void agg_kernel(const unsigned short* __restrict__ XWb,
                                                  const float* __restrict__ dinvf,
                                                  const int* __restrict__ ptr,
                                                  const int* __restrict__ cnt,
                                                  const int2* __restrict__ csr,
                                                  const float* __restrict__ bias,
                                                  float* __restrict__ out, int BN) {
    int h = threadIdx.x >> 5;        // half-wave id 0..7
    int lane = threadIdx.x & 31;     // lane within half-wave
    int n = blockIdx.x * 8 + h;
    if (n >= BN) return;
    int beg = ptr[n];
    int endv = beg + cnt[n];

    float4 acc0 = make_float4(0.f, 0.f, 0.f, 0.f);
    float4 acc1 = make_float4(0.f, 0.f, 0.f, 0.f);
    int i = beg;
    for (; i + 1 < endv; i += 2) {
        int2 e0 = csr[i];
        int2 e1 = csr[i + 1];
        uint2 r0 = *(const uint2*)(XWb + (size_t)e0.x * 128 + lane * 4);
        uint2 r1 = *(const uint2*)(XWb + (size_t)e1.x * 128 + lane * 4);
        float n0 = __int_as_float(e0.y), n1 = __int_as_float(e1.y);
        acc0.x += n0 * bf_lo(r0.x); acc0.y += n0 * bf_hi(r0.x);
        acc0.z += n0 * bf_lo(r0.y); acc0.w += n0 * bf_hi(r0.y);
        acc1.x += n1 * bf_lo(r1.x); acc1.y += n1 * bf_hi(r1.x);
        acc1.z += n1 * bf_lo(r1.y); acc1.w += n1 * bf_hi(r1.y);
    }
    if (i < endv) {
        int2 e0 = csr[i];
        uint2 r0 = *(const uint2*)(XWb + (size_t)e0.x * 128 + lane * 4);
        float n0 = __int_as_float(e0.y);
        acc0.x += n0 * bf_lo(r0.x); acc0.y += n0 * bf_hi(r0.x);
        acc0.z += n0 * bf_lo(r0.y); acc0.w += n0 * bf_hi(r0.y);
    }
    float dn = dinvf[n];
    float sl = dn * dn;
    uint2 rs = *(const uint2*)(XWb + (size_t)n * 128 + lane * 4);
    float4 bb = ((const float4*)bias)[lane];
    float4 o;
    o.x = gelu_exact(acc0.x + acc1.x + sl * bf_lo(rs.x) + bb.x);
    o.y = gelu_exact(acc0.y + acc1.y + sl * bf_hi(rs.x) + bb.y);
    o.z = gelu_exact(acc0.z + acc1.z + sl * bf_lo(rs.y) + bb.z);
    o.w = gelu_exact(acc0.w + acc1.w + sl * bf_hi(rs.y) + bb.w);
    ((float4*)(out + (size_t)n * 128))[lane] = o;
}

// ---------------- launch ----------------

extern "C" void kernel_launch(void* const* d_in, const int* in_sizes, int n_in,
                              void* d_out, int out_size, void* d_ws, size_t ws_size,
                              hipStream_t stream) {
    const float* x = (const float*)d_in[0];
    const int* ei = (const int*)d_in[1];        // harness passes integers as int32
    const float* w = (const float*)d_in[5];
    const float* W1 = (const float*)d_in[7];
    const float* b1 = (const float*)d_in[8];
    const float* W2 = (const float*)d_in[9];
    const float* b2 = (const float*)d_in[10];
    const float* Wres = (const float*)d_in[11];
    const float* bres = (const float*)d_in[12];

    const int BN = in_sizes[0] / DIM;
    const int E = in_sizes[1] / 2;
    const int NBLK = (BN + SCAN_CHUNK - 1) / SCAN_CHUNK;

    // workspace layout (16B aligned); h-buffer lives in d_out.
    char* p = (char*)d_ws;
    unsigned short* Ab = (unsigned short*)p;         p += (size_t)BN * DIM * 2;  // bf16 XW
    unsigned long long* packed = (unsigned long long*)p;  p += (size_t)BN * 8;
    float* dinvf = (float*)p;          p += (size_t)BN * 4;
    int* cnt = (int*)p;                p += (size_t)BN * 4;
    int* ptr = (int*)p;                p += (size_t)BN * 4;
    int* partials = (int*)p;           p += 1024;
    unsigned short* Wt1 = (unsigned short*)p;   p += 128 * 128 * 2;
    unsigned short* Wtr = (unsigned short*)p;   p += 128 * 128 * 2;
    unsigned short* Wt2 = (unsigned short*)p;   p += 128 * 128 * 2;
    int* rank = (int*)p;               p += (size_t)E * 4;
    int2* csr = (int2*)p;              p += (size_t)E * 8;

    float* Bf = (float*)d_out;         // h buffer; fully overwritten by final agg

    const int* dst32 = ei + E;

    hipMemsetAsync(packed, 0, (size_t)BN * 8, stream);

    int tE = (E + 255) / 256;
    int tN = (BN + 255) / 256;

    deg_cnt_kernel<<<tE, 256, 0, stream>>>(dst32, w, packed, rank, E);
    dinv_kernel<<<tN, 256, 0, stream>>>(packed, dinvf, cnt, BN);
    scanA_kernel<<<NBLK, 256, 0, stream>>>(cnt, partials, BN);
    scanB_kernel<<<1, 256, 0, stream>>>(partials, NBLK);
    scanC_kernel<<<NBLK, 256, 0, stream>>>(cnt, partials, ptr, BN);
    fill_kernel<<<tE, 256, 0, stream>>>(ei, w, rank, ptr, dinvf, csr, E);

    wt_kernel<<<64, 256, 0, stream>>>(W1, Wt1);
    wt_kernel<<<64, 256, 0, stream>>>(Wres, Wtr);
    wt_kernel<<<64, 256, 0, stream>>>(W2, Wt2);

    int gemmBlocks = (BN + 63) / 64;
    int aggBlocks = (BN + 7) / 8;

    // layer 1: Ab = bf16(x@W1) ; Bf = gelu(agg(Ab) + b1) ; Bf += 0.3*(x@Wres + bres)
    mfma_gemm_kernel<0><<<gemmBlocks, 256, 0, stream>>>(x, Wt1, nullptr, Ab, nullptr, BN);
    agg_kernel<<<aggBlocks, 256, 0, stream>>>(Ab, dinvf, ptr, cnt, csr, b1, Bf, BN);
    mfma_gemm_kernel<1><<<gemmBlocks, 256, 0, stream>>>(x, Wtr, bres, nullptr, Bf, BN);

    // layer 2: Ab = bf16(Bf@W2) ; out = gelu(agg(Ab) + b2)
    mfma_gemm_kernel<0><<<gemmBlocks, 256, 0, stream>>>(Bf, Wt2, nullptr, Ab, nullptr, BN);
    agg_kernel<<<aggBlocks, 256, 0, stream>>>(Ab, dinvf, ptr, cnt, csr, b2, (float*)d_out, BN);
}

// Round 7
// 487.467 us; speedup vs baseline: 2.2192x; 1.0660x over previous
//
#include <hip/hip_runtime.h>
#include <math.h>

#define DIM 128
#define SCAN_CHUNK 4096  // 256 threads * 16 elems

typedef __attribute__((ext_vector_type(8))) short short8;
typedef __attribute__((ext_vector_type(4))) float f32x4;

__device__ __forceinline__ float gelu_exact(float v) {
    return 0.5f * v * (1.0f + erff(v * 0.70710678118654752f));
}

// round-to-nearest-even fp32 -> bf16 bits (finite inputs)
__device__ __forceinline__ unsigned short f2bf(float f) {
    unsigned int u = __float_as_uint(f);
    return (unsigned short)((u + 0x7FFFu + ((u >> 16) & 1u)) >> 16);
}
__device__ __forceinline__ float bf_lo(unsigned int v) { return __uint_as_float(v << 16); }
__device__ __forceinline__ float bf_hi(unsigned int v) { return __uint_as_float(v & 0xFFFF0000u); }

// ---------------- weight transpose + bf16 (3 matrices, one launch) ----------------

__global__ __launch_bounds__(256) void wt3_kernel(const float* __restrict__ W1,
                                                  const float* __restrict__ Wres,
                                                  const float* __restrict__ W2,
                                                  unsigned short* __restrict__ Wt1,
                                                  unsigned short* __restrict__ Wtr,
                                                  unsigned short* __restrict__ Wt2) {
    int b = blockIdx.x;
    const float* W = (b < 64) ? W1 : (b < 128) ? Wres : W2;
    unsigned short* Wt = (b < 64) ? Wt1 : (b < 128) ? Wtr : Wt2;
    int idx = (b & 63) * 256 + threadIdx.x;  // idx = r*128 + c
    int r = idx >> 7, c = idx & 127;
    Wt[c * 128 + r] = f2bf(W[idx]);
}

// ---------------- MFMA GEMM body: [BN,128] @ [128,128] via bf16 16x16x32 ----------
// MODE 0: outb = bf16(X @ W)        MODE 2: Bf = 0.3f*(X@W + bias)   (init)

template <int MODE>
__device__ __forceinline__ void gemm_body(const float* __restrict__ X,
                                          const unsigned short* __restrict__ Wt,
                                          const float* __restrict__ bias,
                                          unsigned short* __restrict__ outb,
                                          float* __restrict__ Bf, int bid, int BN) {
    int tid = threadIdx.x;
    int w = tid >> 6, l = tid & 63;
    int l15 = l & 15, kg = l >> 4;
    int row0 = bid * 64 + w * 16;

    int rowA = row0 + l15;
    if (rowA > BN - 1) rowA = BN - 1;
    const float* ap = X + (size_t)rowA * 128 + kg * 8;

    f32x4 acc[8];
#pragma unroll
    for (int nt = 0; nt < 8; nt++) acc[nt] = (f32x4){0.f, 0.f, 0.f, 0.f};

#pragma unroll
    for (int ks = 0; ks < 4; ks++) {
        float4 a0 = *(const float4*)(ap + ks * 32);
        float4 a1 = *(const float4*)(ap + ks * 32 + 4);
        short8 aF;
        aF[0] = (short)f2bf(a0.x); aF[1] = (short)f2bf(a0.y);
        aF[2] = (short)f2bf(a0.z); aF[3] = (short)f2bf(a0.w);
        aF[4] = (short)f2bf(a1.x); aF[5] = (short)f2bf(a1.y);
        aF[6] = (short)f2bf(a1.z); aF[7] = (short)f2bf(a1.w);
#pragma unroll
        for (int nt = 0; nt < 8; nt++) {
            int colB = nt * 16 + l15;
            uint4 bu = *(const uint4*)(Wt + (size_t)colB * 128 + ks * 32 + kg * 8);
            short8 bF = __builtin_bit_cast(short8, bu);
            acc[nt] = __builtin_amdgcn_mfma_f32_16x16x32_bf16(aF, bF, acc[nt], 0, 0, 0);
        }
    }

#pragma unroll
    for (int nt = 0; nt < 8; nt++) {
        int col = nt * 16 + l15;
#pragma unroll
        for (int r = 0; r < 4; r++) {
            int row = row0 + kg * 4 + r;
            if (row >= BN) continue;
            size_t idx = (size_t)row * 128 + col;
            if (MODE == 0) {
                outb[idx] = f2bf(acc[nt][r]);
            } else {
                Bf[idx] = 0.3f * (acc[nt][r] + bias[col]);
            }
        }
    }
}

template <int MODE>
__global__ __launch_bounds__(256) void mfma_gemm_kernel(const float* __restrict__ X,
                                                        const unsigned short* __restrict__ Wt,
                                                        const float* __restrict__ bias,
                                                        unsigned short* __restrict__ outb,
                                                        float* __restrict__ Bf, int BN) {
    gemm_body<MODE>(X, Wt, bias, outb, Bf, blockIdx.x, BN);
}

// ---------------- phase0: horizontal fusion {gemm1, gemm_res-init, deg_cnt} -------
// deg path: packed[d] = (count<<32) | sum_w in 2^26 fixed point; old>>32 = rank.

__global__ __launch_bounds__(256) void phase0_kernel(const float* __restrict__ x,
                                                     const unsigned short* __restrict__ Wt1,
                                                     const unsigned short* __restrict__ Wtr,
                                                     const float* __restrict__ bres,
                                                     unsigned short* __restrict__ Ab,
                                                     float* __restrict__ Bf,
                                                     const int* __restrict__ dst,
                                                     const float* __restrict__ w,
                                                     unsigned long long* __restrict__ packed,
                                                     int* __restrict__ rank,
                                                     int BN, int E, int gB) {
    int b = blockIdx.x;
    if (b < gB) { gemm_body<0>(x, Wt1, nullptr, Ab, nullptr, b, BN); return; }
    b -= gB;
    if (b < gB) { gemm_body<2>(x, Wtr, bres, nullptr, Bf, b, BN); return; }
    b -= gB;
    int e0 = b * 512 + threadIdx.x;
#pragma unroll
    for (int it = 0; it < 2; it++) {
        int e = e0 + it * 256;
        if (e < E) {
            int d = dst[e];
            unsigned long long inc =
                (1ull << 32) | (unsigned long long)(unsigned int)(w[e] * 67108864.0f);
            unsigned long long old = atomicAdd(&packed[d], inc);
            rank[e] = (int)(old >> 32);
        }
    }
}

// ---------------- scan stage A (fused with dinv/cnt unpack) ----------------

__global__ __launch_bounds__(256) void scanAD_kernel(const unsigned long long* __restrict__ packed,
                                                     float* __restrict__ dinvf,
                                                     int* __restrict__ cnt,
                                                     int* __restrict__ partials, int BN) {
    int tid = threadIdx.x;
    int base = blockIdx.x * SCAN_CHUNK;
    int sum = 0;
#pragma unroll
    for (int i = 0; i < 16; i++) {
        int ii = base + i * 256 + tid;
        if (ii < BN) {
            unsigned long long v = packed[ii];
            int c = (int)(v >> 32);
            cnt[ii] = c;
            dinvf[ii] = rsqrtf((float)(unsigned int)(v & 0xFFFFFFFFu) * (1.0f / 67108864.0f) + 1.0f);
            sum += c;
        }
    }
    __shared__ int lds[4];
#pragma unroll
    for (int off = 32; off; off >>= 1) sum += __shfl_down(sum, off, 64);
    if ((tid & 63) == 0) lds[tid >> 6] = sum;
    __syncthreads();
    if (tid == 0) partials[blockIdx.x] = lds[0] + lds[1] + lds[2] + lds[3];
}

__global__ __launch_bounds__(256) void scanB_kernel(int* __restrict__ partials, int nblk) {
    __shared__ int lds[256];
    int tid = threadIdx.x;
    int v = (tid < nblk) ? partials[tid] : 0;
    lds[tid] = v;
    __syncthreads();
#pragma unroll
    for (int off = 1; off < 256; off <<= 1) {
        int t = (tid >= off) ? lds[tid - off] : 0;
        __syncthreads();
        lds[tid] += t;
        __syncthreads();
    }
    if (tid < nblk) partials[tid] = lds[tid] - v;  // exclusive
}

__global__ __launch_bounds__(256) void scanC_kernel(const int* __restrict__ cnt,
                                                    const int* __restrict__ partials,
                                                    int* __restrict__ ptr, int BN) {
    __shared__ int lds[256];
    int tid = threadIdx.x;
    int base = blockIdx.x * SCAN_CHUNK;
    int idx0 = base + tid * 16;
    int v[16];
    int tsum = 0;
#pragma unroll
    for (int j = 0; j < 16; j++) {
        int ii = idx0 + j;
        v[j] = (ii < BN) ? cnt[ii] : 0;
        tsum += v[j];
    }
    lds[tid] = tsum;
    __syncthreads();
#pragma unroll
    for (int off = 1; off < 256; off <<= 1) {
        int t = (tid >= off) ? lds[tid - off] : 0;
        __syncthreads();
        lds[tid] += t;
        __syncthreads();
    }
    int excl = lds[tid] - tsum + partials[blockIdx.x];
#pragma unroll
    for (int j = 0; j < 16; j++) {
        int ii = idx0 + j;
        if (ii < BN) ptr[ii] = excl;
        excl += v[j];
    }
}

// atomic-free fill: pos = ptr[d] + rank[e]; one packed int2 {src, nrm} per edge
__global__ void fill_kernel(const int* __restrict__ ei, const float* __restrict__ w,
                            const int* __restrict__ rank, const int* __restrict__ ptr,
                            const float* __restrict__ dinvf,
                            int2* __restrict__ csr, int E) {
    int e = blockIdx.x * blockDim.x + threadIdx.x;
    if (e >= E) return;
    int s = ei[e];
    int d = ei[(size_t)E + e];
    int pos = ptr[d] + rank[e];
    float nrm = dinvf[s] * w[e] * dinvf[d];
    csr[pos] = make_int2(s, __float_as_int(nrm));
}

// ---------------- aggregation: half-wave (32 lanes) per node, bf16 gather, 4-deep ----
// ACCMODE 0: out = gelu(...)        ACCMODE 1: out += gelu(...)

template <int ACCMODE>
__global__ __launch_bounds__(256) void agg_kernel(const unsigned short* __restrict__ XWb,
                                                  const float* __restrict__ dinvf,
                                                  const int* __restrict__ ptr,
                                                  const int* __restrict__ cnt,
                                                  const int2* __restrict__ csr,
                                                  const float* __restrict__ bias,
                                                  float* __restrict__ out, int BN) {
    int h = threadIdx.x >> 5;        // half-wave id 0..7
    int lane = threadIdx.x & 31;     // lane within half-wave
    int n = blockIdx.x * 8 + h;
    if (n >= BN) return;
    int beg = ptr[n];
    int endv = beg + cnt[n];

    float4 a0 = make_float4(0.f, 0.f, 0.f, 0.f);
    float4 a1 = make_float4(0.f, 0.f, 0.f, 0.f);
    float4 a2 = make_float4(0.f, 0.f, 0.f, 0.f);
    float4 a3 = make_float4(0.f, 0.f, 0.f, 0.f);
    int i = beg;
    for (; i + 3 < endv; i += 4) {
        int2 e0 = csr[i], e1 = csr[i + 1], e2 = csr[i + 2], e3 = csr[i + 3];
        uint2 r0 = *(const uint2*)(XWb + (size_t)e0.x * 128 + lane * 4);
        uint2 r1 = *(const uint2*)(XWb + (size_t)e1.x * 128 + lane * 4);
        uint2 r2 = *(const uint2*)(XWb + (size_t)e2.x * 128 + lane * 4);
        uint2 r3 = *(const uint2*)(XWb + (size_t)e3.x * 128 + lane * 4);
        float n0 = __int_as_float(e0.y), n1 = __int_as_float(e1.y);
        float n2 = __int_as_float(e2.y), n3 = __int_as_float(e3.y);
        a0.x += n0 * bf_lo(r0.x); a0.y += n0 * bf_hi(r0.x);
        a0.z += n0 * bf_lo(r0.y); a0.w += n0 * bf_hi(r0.y);
        a1.x += n1 * bf_lo(r1.x); a1.y += n1 * bf_hi(r1.x);
        a1.z += n1 * bf_lo(r1.y); a1.w += n1 * bf_hi(r1.y);
        a2.x += n2 * bf_lo(r2.x); a2.y += n2 * bf_hi(r2.x);
        a2.z += n2 * bf_lo(r2.y); a2.w += n2 * bf_hi(r2.y);
        a3.x += n3 * bf_lo(r3.x); a3.y += n3 * bf_hi(r3.x);
        a3.z += n3 * bf_lo(r3.y); a3.w += n3 * bf_hi(r3.y);
    }
    for (; i < endv; i++) {
        int2 e0 = csr[i];
        uint2 r0 = *(const uint2*)(XWb + (size_t)e0.x * 128 + lane * 4);
        float n0 = __int_as_float(e0.y);
        a0.x += n0 * bf_lo(r0.x); a0.y += n0 * bf_hi(r0.x);
        a0.z += n0 * bf_lo(r0.y); a0.w += n0 * bf_hi(r0.y);
    }
    float dn = dinvf[n];
    float sl = dn * dn;
    uint2 rs = *(const uint2*)(XWb + (size_t)n * 128 + lane * 4);
    float4 bb = ((const float4*)bias)[lane];
    float4 o;
    o.x = gelu_exact(a0.x + a1.x + a2.x + a3.x + sl * bf_lo(rs.x) + bb.x);
    o.y = gelu_exact(a0.y + a1.y + a2.y + a3.y + sl * bf_hi(rs.x) + bb.y);
    o.z = gelu_exact(a0.z + a1.z + a2.z + a3.z + sl * bf_lo(rs.y) + bb.z);
    o.w = gelu_exact(a0.w + a1.w + a2.w + a3.w + sl * bf_hi(rs.y) + bb.w);
    float4* op = (float4*)(out + (size_t)n * 128) + lane;
    if (ACCMODE == 1) {
        float4 prev = *op;
        o.x += prev.x; o.y += prev.y; o.z += prev.z; o.w += prev.w;
    }
    *op = o;
}

// ---------------- launch ----------------

extern "C" void kernel_launch(void* const* d_in, const int* in_sizes, int n_in,
                              void* d_out, int out_size, void* d_ws, size_t ws_size,
                              hipStream_t stream) {
    const float* x = (const float*)d_in[0];
    const int* ei = (const int*)d_in[1];        // harness passes integers as int32
    const float* w = (const float*)d_in[5];
    const float* W1 = (const float*)d_in[7];
    const float* b1 = (const float*)d_in[8];
    const float* W2 = (const float*)d_in[9];
    const float* b2 = (const float*)d_in[10];
    const float* Wres = (const float*)d_in[11];
    const float* bres = (const float*)d_in[12];

    const int BN = in_sizes[0] / DIM;
    const int E = in_sizes[1] / 2;
    const int NBLK = (BN + SCAN_CHUNK - 1) / SCAN_CHUNK;

    // workspace layout (16B aligned); h-buffer lives in d_out.
    char* p = (char*)d_ws;
    unsigned short* Ab = (unsigned short*)p;         p += (size_t)BN * DIM * 2;  // bf16 XW
    unsigned long long* packed = (unsigned long long*)p;  p += (size_t)BN * 8;
    float* dinvf = (float*)p;          p += (size_t)BN * 4;
    int* cnt = (int*)p;                p += (size_t)BN * 4;
    int* ptr = (int*)p;                p += (size_t)BN * 4;
    int* partials = (int*)p;           p += 1024;
    unsigned short* Wt1 = (unsigned short*)p;   p += 128 * 128 * 2;
    unsigned short* Wtr = (unsigned short*)p;   p += 128 * 128 * 2;
    unsigned short* Wt2 = (unsigned short*)p;   p += 128 * 128 * 2;
    int* rank = (int*)p;               p += (size_t)E * 4;
    int2* csr = (int2*)p;              p += (size_t)E * 8;

    float* Bf = (float*)d_out;         // h buffer; fully written by phase0 res-init

    const int* dst32 = ei + E;

    hipMemsetAsync(packed, 0, (size_t)BN * 8, stream);

    int tE = (E + 255) / 256;
    int gB = (BN + 63) / 64;
    int degBlocks = (E + 511) / 512;
    int aggBlocks = (BN + 7) / 8;

    wt3_kernel<<<192, 256, 0, stream>>>(W1, Wres, W2, Wt1, Wtr, Wt2);

    // phase0: Ab = bf16(x@W1)  ||  Bf = 0.3*(x@Wres+bres)  ||  deg/rank atomics
    phase0_kernel<<<2 * gB + degBlocks, 256, 0, stream>>>(x, Wt1, Wtr, bres, Ab, Bf,
                                                          dst32, w, packed, rank, BN, E, gB);

    scanAD_kernel<<<NBLK, 256, 0, stream>>>(packed, dinvf, cnt, partials, BN);
    scanB_kernel<<<1, 256, 0, stream>>>(partials, NBLK);
    scanC_kernel<<<NBLK, 256, 0, stream>>>(cnt, partials, ptr, BN);
    fill_kernel<<<tE, 256, 0, stream>>>(ei, w, rank, ptr, dinvf, csr, E);

    // layer 1 finish: Bf += gelu(agg(Ab) + b1)
    agg_kernel<1><<<aggBlocks, 256, 0, stream>>>(Ab, dinvf, ptr, cnt, csr, b1, Bf, BN);

    // layer 2: Ab = bf16(Bf@W2) ; out = gelu(agg(Ab) + b2)
    mfma_gemm_kernel<0><<<gB, 256, 0, stream>>>(Bf, Wt2, nullptr, Ab, nullptr, BN);
    agg_kernel<0><<<aggBlocks, 256, 0, stream>>>(Ab, dinvf, ptr, cnt, csr, b2, (float*)d_out, BN);
}